// Round 1
// baseline (156.174 us; speedup 1.0000x reference)
//
#include <hip/hip_runtime.h>
#include <hip/hip_bf16.h>
#include <math.h>
#include <stdint.h>

// ScaledDotProductAttention: B=2, H=16, S=2048, D=64, fp32 in/out.
// Flash-attention fwd, bf16 MFMA (16x16x32), online softmax.
// Block = 256 threads (4 waves); each wave owns 16 q-rows; block owns 64.
// Grid = (S/64, B*H).

#define S_LEN 2048
#define DK 64
#define QBLK 64
#define KVBLK 64
#define NW 4
#define LOG2E 1.44269504088896340736f

typedef __attribute__((ext_vector_type(4))) float f32x4;
typedef __attribute__((ext_vector_type(8))) __bf16 bf16x8;
typedef __attribute__((ext_vector_type(4))) __bf16 bf16x4;

__global__ __launch_bounds__(256, 4)
void attn_fwd_kernel(const float* __restrict__ Qg, const float* __restrict__ Kg,
                     const float* __restrict__ Vg, float* __restrict__ Og)
{
    // K tile: row-major [k][d], XOR-swizzled: elem = r*64 + (d ^ ((r&7)<<3))
    __shared__ __align__(16) __bf16 Kl[64 * 64];
    // V tile: TRANSPOSED [d][k], swizzled: elem = d*64 + (k ^ ((d&15)<<2))
    __shared__ __align__(16) __bf16 Vt[64 * 64];
    // P round-trip, per-wave [16][64], swizzled like K
    __shared__ __align__(16) __bf16 Pl[NW * 16 * 64];

    const int tid  = threadIdx.x;
    const int lane = tid & 63;
    const int w    = tid >> 6;
    const int l15  = lane & 15;
    const int l4   = lane >> 4;

    const int qt = blockIdx.x;
    const int bh = blockIdx.y;
    const size_t base = (size_t)bh * (S_LEN * DK);
    const int q0 = qt * QBLK + w * 16;   // this wave's first q row

    // ---- Q fragments in registers (scale 1/8 folded in; exact pow2) ----
    // A-frag layout for 16x16x32: lane holds A[l&15][8*(l>>4)+i]
    bf16x8 qfrag[2];
    {
        const float* qrow = Qg + base + (size_t)(q0 + l15) * DK;
        #pragma unroll
        for (int kk = 0; kk < 2; ++kk) {
            const int d0 = kk * 32 + l4 * 8;
            float4 a = *(const float4*)(qrow + d0);
            float4 b = *(const float4*)(qrow + d0 + 4);
            bf16x8 f;
            f[0] = (__bf16)(a.x * 0.125f); f[1] = (__bf16)(a.y * 0.125f);
            f[2] = (__bf16)(a.z * 0.125f); f[3] = (__bf16)(a.w * 0.125f);
            f[4] = (__bf16)(b.x * 0.125f); f[5] = (__bf16)(b.y * 0.125f);
            f[6] = (__bf16)(b.z * 0.125f); f[7] = (__bf16)(b.w * 0.125f);
            qfrag[kk] = f;
        }
    }

    // Accumulator: O tile 16x64 as 4 col-chunks. C/D layout:
    // row = (l>>4)*4 + j, col = l&15  -> lane holds rows l4*4+j, col dc*16+l15
    f32x4 acc[4] = {};
    float m_j[4], l_j[4];
    #pragma unroll
    for (int j = 0; j < 4; ++j) { m_j[j] = -INFINITY; l_j[j] = 0.f; }

    #pragma unroll 1
    for (int t = 0; t < S_LEN / KVBLK; ++t) {
        const int kv0 = t * KVBLK;
        __syncthreads();   // previous iteration's LDS reads done

        // ---- stage K tile (row-major, coalesced float4 loads) ----
        #pragma unroll
        for (int i = 0; i < 4; ++i) {
            const int idx = tid + 256 * i;
            const int r = idx >> 4, c = idx & 15;           // row, float4-chunk
            float4 kv = *(const float4*)(Kg + base + (size_t)(kv0 + r) * DK + c * 4);
            bf16x4 pk;
            pk[0] = (__bf16)kv.x; pk[1] = (__bf16)kv.y;
            pk[2] = (__bf16)kv.z; pk[3] = (__bf16)kv.w;
            const int eo = r * 64 + ((c * 4) ^ ((r & 7) << 3));
            *(bf16x4*)(&Kl[eo]) = pk;
        }

        // ---- stage V tile transposed: lane d = tid&63 reads a column ----
        {
            const int d = tid & 63;
            const int kq = tid >> 6;
            #pragma unroll
            for (int i = 0; i < 4; ++i) {
                const int k0 = kq * 4 + 16 * i;
                const float* vp = Vg + base + (size_t)(kv0 + k0) * DK + d;
                float v0 = vp[0], v1 = vp[DK], v2 = vp[2 * DK], v3 = vp[3 * DK];
                bf16x4 pv;
                pv[0] = (__bf16)v0; pv[1] = (__bf16)v1;
                pv[2] = (__bf16)v2; pv[3] = (__bf16)v3;
                const int eo = d * 64 + (k0 ^ ((d & 15) << 2));
                *(bf16x4*)(&Vt[eo]) = pv;
            }
        }
        __syncthreads();

        // ---- S = Q K^T : 4 col-tiles (kc) x 2 d-halves (kk) ----
        // B-frag: lane holds B[8*l4+i][l15] = K[kc*16+l15][kk*32+8*l4+i]
        f32x4 s[4];
        #pragma unroll
        for (int kc = 0; kc < 4; ++kc) {
            f32x4 a = {};
            #pragma unroll
            for (int kk = 0; kk < 2; ++kk) {
                const int row = kc * 16 + l15;
                const int eo = row * 64 + ((kk * 32 + l4 * 8) ^ ((row & 7) << 3));
                bf16x8 kb = *(const bf16x8*)(&Kl[eo]);
                a = __builtin_amdgcn_mfma_f32_16x16x32_bf16(qfrag[kk], kb, a, 0, 0, 0);
            }
            s[kc] = a;
        }

        // ---- online softmax (rows spread over 16 lanes sharing l4) ----
        #pragma unroll
        for (int j = 0; j < 4; ++j) {
            float v = fmaxf(fmaxf(s[0][j], s[1][j]), fmaxf(s[2][j], s[3][j]));
            v = fmaxf(v, __shfl_xor(v, 1));
            v = fmaxf(v, __shfl_xor(v, 2));
            v = fmaxf(v, __shfl_xor(v, 4));
            v = fmaxf(v, __shfl_xor(v, 8));
            const float mn = fmaxf(m_j[j], v);
            const float alpha = exp2f((m_j[j] - mn) * LOG2E);
            m_j[j] = mn;
            float rs = 0.f;
            #pragma unroll
            for (int kc = 0; kc < 4; ++kc) {
                float p = exp2f((s[kc][j] - mn) * LOG2E);
                s[kc][j] = p;
                rs += p;
            }
            rs += __shfl_xor(rs, 1);
            rs += __shfl_xor(rs, 2);
            rs += __shfl_xor(rs, 4);
            rs += __shfl_xor(rs, 8);
            l_j[j] = l_j[j] * alpha + rs;
            #pragma unroll
            for (int dc = 0; dc < 4; ++dc) acc[dc][j] *= alpha;
        }

        // ---- P -> LDS (re-layout C/D -> A frag), per-wave region ----
        __bf16* Pw = &Pl[w * 16 * 64];
        #pragma unroll
        for (int j = 0; j < 4; ++j) {
            const int row = l4 * 4 + j;
            #pragma unroll
            for (int kc = 0; kc < 4; ++kc) {
                const int col = kc * 16 + l15;
                Pw[row * 64 + (col ^ ((row & 7) << 3))] = (__bf16)s[kc][j];
            }
        }
        // within-wave LDS write->read: program order + compiler waitcnt suffice

        // ---- O += P V : K-dim 64 as 2 halves (kk2), 4 d col-chunks ----
        #pragma unroll
        for (int kk2 = 0; kk2 < 2; ++kk2) {
            const int peo = l15 * 64 + ((kk2 * 32 + l4 * 8) ^ ((l15 & 7) << 3));
            bf16x8 pa = *(const bf16x8*)(&Pw[peo]);
            #pragma unroll
            for (int dc = 0; dc < 4; ++dc) {
                const int d = dc * 16 + l15;
                const int sw = (d & 15) << 2;
                const int kbase = kk2 * 32 + l4 * 8;
                bf16x4 vlo = *(const bf16x4*)(&Vt[d * 64 + (kbase ^ sw)]);
                bf16x4 vhi = *(const bf16x4*)(&Vt[d * 64 + ((kbase + 4) ^ sw)]);
                bf16x8 vb = __builtin_shufflevector(vlo, vhi, 0, 1, 2, 3, 4, 5, 6, 7);
                acc[dc] = __builtin_amdgcn_mfma_f32_16x16x32_bf16(pa, vb, acc[dc], 0, 0, 0);
            }
        }
    }

    // ---- epilogue: O = acc / l ----
    float* op = Og + base;
    #pragma unroll
    for (int j = 0; j < 4; ++j) {
        const size_t row = (size_t)(q0 + l4 * 4 + j) * DK;
        const float invl = 1.0f / l_j[j];
        #pragma unroll
        for (int dc = 0; dc < 4; ++dc)
            op[row + dc * 16 + l15] = acc[dc][j] * invl;
    }
}

extern "C" void kernel_launch(void* const* d_in, const int* in_sizes, int n_in,
                              void* d_out, int out_size, void* d_ws, size_t ws_size,
                              hipStream_t stream) {
    const float* q = (const float*)d_in[0];
    const float* k = (const float*)d_in[1];
    const float* v = (const float*)d_in[2];
    float* o = (float*)d_out;
    const int bh = in_sizes[0] / (S_LEN * DK);   // = 32 for B=2,H=16
    dim3 grid(S_LEN / QBLK, bh);
    attn_fwd_kernel<<<grid, dim3(256), 0, stream>>>(q, k, v, o);
}

// Round 2
// 89.294 us; speedup vs baseline: 1.7490x; 1.7490x over previous
//
#include <hip/hip_runtime.h>
#include <hip/hip_bf16.h>
#include <math.h>
#include <stdint.h>

// ScaledDotProductAttention: B=2, H=16, S=2048, D=64, fp32 in/out.
// Flash-attention fwd, bf16 MFMA (16x16x32), online softmax.
// Swapped QK^T (S^T = K Q^T) so each lane owns one q-column -> lane-local softmax.
// Double-buffered K/V staging with register prefetch (one barrier per tile).
// Block = 256 threads (4 waves); each wave owns 16 q-rows; block owns 64.
// Grid = (S/64, B*H).

#define S_LEN 2048
#define DK 64
#define QBLK 64
#define KVBLK 64
#define NT (S_LEN / KVBLK)
#define NW 4
#define LOG2E 1.44269504088896340736f

typedef __attribute__((ext_vector_type(4))) float f32x4;
typedef __attribute__((ext_vector_type(8))) __bf16 bf16x8;
typedef __attribute__((ext_vector_type(4))) __bf16 bf16x4;

__global__ __launch_bounds__(256, 4)
void attn_fwd_kernel(const float* __restrict__ Qg, const float* __restrict__ Kg,
                     const float* __restrict__ Vg, float* __restrict__ Og)
{
    // K tile: row-major [k][d], XOR-swizzled: elem = r*64 + (d ^ ((r&7)<<3))
    __shared__ __align__(16) __bf16 Kl[2][64 * 64];
    // V tile: TRANSPOSED [d][k], swizzled: elem = d*64 + (k ^ ((d&15)<<2))
    __shared__ __align__(16) __bf16 Vt[2][64 * 64];
    // P round-trip, per-wave [16 q][64 k], swizzled: q*64 + (k ^ ((q&7)<<3))
    __shared__ __align__(16) __bf16 Pl[NW][16 * 64];

    const int tid  = threadIdx.x;
    const int lane = tid & 63;
    const int w    = tid >> 6;
    const int l15  = lane & 15;
    const int l4   = lane >> 4;

    const int qt = blockIdx.x;
    const int bh = blockIdx.y;
    const size_t base = (size_t)bh * (S_LEN * DK);
    const int q0 = qt * QBLK + w * 16;   // this wave's first q row

    // ---- Q fragments (B-operand of swapped QK^T). Layout identical to the
    // A-frag pattern: lane holds Q[q0+l15][kk*32 + 8*l4 + i].
    // Scale 1/sqrt(64) * log2(e) folded in -> logits already in log2 domain.
    bf16x8 qfrag[2];
    {
        const float* qrow = Qg + base + (size_t)(q0 + l15) * DK;
        const float sc = 0.125f * LOG2E;
        #pragma unroll
        for (int kk = 0; kk < 2; ++kk) {
            const int d0 = kk * 32 + l4 * 8;
            float4 a = *(const float4*)(qrow + d0);
            float4 b = *(const float4*)(qrow + d0 + 4);
            bf16x8 f;
            f[0] = (__bf16)(a.x * sc); f[1] = (__bf16)(a.y * sc);
            f[2] = (__bf16)(a.z * sc); f[3] = (__bf16)(a.w * sc);
            f[4] = (__bf16)(b.x * sc); f[5] = (__bf16)(b.y * sc);
            f[6] = (__bf16)(b.z * sc); f[7] = (__bf16)(b.w * sc);
            qfrag[kk] = f;
        }
    }

    // O accumulator: lane holds O[q-local = 4*l4+j][d = dc*16+l15]
    f32x4 acc[4] = {};
    // online-softmax state, per lane, for q-column l15 (replicated over l4)
    float m_run = -INFINITY, l_run = 0.f;

    // ---- staging: prefetch to regs, convert+write later ----
    float4 kpre[4];
    float  vpre[4][4];
    const int vd = tid & 63;          // V: this thread owns column d = vd
    const int vkq = tid >> 6;

    auto issueLoads = [&](int t) {
        const int kv0 = t * KVBLK;
        #pragma unroll
        for (int i = 0; i < 4; ++i) {
            const int idx = tid + 256 * i;
            const int r = idx >> 4, c = idx & 15;
            kpre[i] = *(const float4*)(Kg + base + (size_t)(kv0 + r) * DK + c * 4);
        }
        #pragma unroll
        for (int i = 0; i < 4; ++i) {
            const int k0 = vkq * 4 + 16 * i;
            const float* vp = Vg + base + (size_t)(kv0 + k0) * DK + vd;
            vpre[i][0] = vp[0];      vpre[i][1] = vp[DK];
            vpre[i][2] = vp[2 * DK]; vpre[i][3] = vp[3 * DK];
        }
    };
    auto writeTile = [&](int b) {
        #pragma unroll
        for (int i = 0; i < 4; ++i) {
            const int idx = tid + 256 * i;
            const int r = idx >> 4, c = idx & 15;
            bf16x4 pk;
            pk[0] = (__bf16)kpre[i].x; pk[1] = (__bf16)kpre[i].y;
            pk[2] = (__bf16)kpre[i].z; pk[3] = (__bf16)kpre[i].w;
            *(bf16x4*)(&Kl[b][r * 64 + ((c * 4) ^ ((r & 7) << 3))]) = pk;
        }
        #pragma unroll
        for (int i = 0; i < 4; ++i) {
            const int k0 = vkq * 4 + 16 * i;
            bf16x4 pv;
            pv[0] = (__bf16)vpre[i][0]; pv[1] = (__bf16)vpre[i][1];
            pv[2] = (__bf16)vpre[i][2]; pv[3] = (__bf16)vpre[i][3];
            *(bf16x4*)(&Vt[b][vd * 64 + (k0 ^ ((vd & 15) << 2))]) = pv;
        }
    };

    issueLoads(0);
    writeTile(0);
    __syncthreads();

    int cur = 0;
    #pragma unroll 1
    for (int t = 0; t < NT; ++t) {
        if (t + 1 < NT) issueLoads(t + 1);   // prefetch next tile into regs

        // ---- S^T = K Q^T : lane holds S^T[k = kc*16+4*l4+j][q = l15] ----
        f32x4 s[4];
        #pragma unroll
        for (int kc = 0; kc < 4; ++kc) {
            f32x4 a = {};
            #pragma unroll
            for (int kk = 0; kk < 2; ++kk) {
                const int row = kc * 16 + l15;
                const int eo = row * 64 + ((kk * 32 + l4 * 8) ^ ((row & 7) << 3));
                bf16x8 kb = *(const bf16x8*)(&Kl[cur][eo]);
                a = __builtin_amdgcn_mfma_f32_16x16x32_bf16(kb, qfrag[kk], a, 0, 0, 0);
            }
            s[kc] = a;
        }

        // ---- lane-local online softmax for q-column l15 ----
        float vmax = fmaxf(fmaxf(fmaxf(s[0][0], s[0][1]), fmaxf(s[0][2], s[0][3])),
                           fmaxf(fmaxf(s[1][0], s[1][1]), fmaxf(s[1][2], s[1][3])));
        vmax = fmaxf(vmax,
                     fmaxf(fmaxf(fmaxf(s[2][0], s[2][1]), fmaxf(s[2][2], s[2][3])),
                           fmaxf(fmaxf(s[3][0], s[3][1]), fmaxf(s[3][2], s[3][3]))));
        vmax = fmaxf(vmax, __shfl_xor(vmax, 16));
        vmax = fmaxf(vmax, __shfl_xor(vmax, 32));
        const float mn = fmaxf(m_run, vmax);
        const float alpha = __builtin_amdgcn_exp2f(m_run - mn);
        m_run = mn;
        float rs = 0.f;
        #pragma unroll
        for (int kc = 0; kc < 4; ++kc) {
            #pragma unroll
            for (int j = 0; j < 4; ++j) {
                const float p = __builtin_amdgcn_exp2f(s[kc][j] - mn);
                s[kc][j] = p;
                rs += p;
            }
        }
        rs += __shfl_xor(rs, 16);
        rs += __shfl_xor(rs, 32);
        l_run = l_run * alpha + rs;

        // broadcast alpha to C/D row layout and rescale O
        float al[4];
        #pragma unroll
        for (int j = 0; j < 4; ++j) al[j] = __shfl(alpha, 4 * l4 + j);
        #pragma unroll
        for (int dc = 0; dc < 4; ++dc) {
            #pragma unroll
            for (int j = 0; j < 4; ++j) acc[dc][j] *= al[j];
        }

        // ---- P -> LDS: lane writes row q=l15, k-run [kc*16+4*l4, +4) ----
        __bf16* Pw = Pl[w];
        #pragma unroll
        for (int kc = 0; kc < 4; ++kc) {
            bf16x4 pp;
            pp[0] = (__bf16)s[kc][0]; pp[1] = (__bf16)s[kc][1];
            pp[2] = (__bf16)s[kc][2]; pp[3] = (__bf16)s[kc][3];
            const int kbase = kc * 16 + 4 * l4;
            *(bf16x4*)(&Pw[l15 * 64 + (kbase ^ ((l15 & 7) << 3))]) = pp;
        }
        // within-wave LDS write->read: program order + compiler waitcnt suffice

        // ---- O += P V : A = P[q][k] from Pw, B = V[k][d] from Vt ----
        #pragma unroll
        for (int kk2 = 0; kk2 < 2; ++kk2) {
            const int peo = l15 * 64 + ((kk2 * 32 + l4 * 8) ^ ((l15 & 7) << 3));
            bf16x8 pa = *(const bf16x8*)(&Pw[peo]);
            #pragma unroll
            for (int dc = 0; dc < 4; ++dc) {
                const int d = dc * 16 + l15;
                const int sw = (d & 15) << 2;
                const int kbase = kk2 * 32 + l4 * 8;
                bf16x4 vlo = *(const bf16x4*)(&Vt[cur][d * 64 + (kbase ^ sw)]);
                bf16x4 vhi = *(const bf16x4*)(&Vt[cur][d * 64 + ((kbase + 4) ^ sw)]);
                bf16x8 vb = __builtin_shufflevector(vlo, vhi, 0, 1, 2, 3, 4, 5, 6, 7);
                acc[dc] = __builtin_amdgcn_mfma_f32_16x16x32_bf16(pa, vb, acc[dc], 0, 0, 0);
            }
        }

        if (t + 1 < NT) writeTile(cur ^ 1);  // convert + store next tile
        __syncthreads();
        cur ^= 1;
    }

    // ---- epilogue: O = acc / l  (l lives in lane with l15 == q-local) ----
    float* op = Og + base;
    #pragma unroll
    for (int j = 0; j < 4; ++j) {
        const size_t row = (size_t)(q0 + l4 * 4 + j) * DK;
        const float invl = 1.0f / __shfl(l_run, 4 * l4 + j);
        #pragma unroll
        for (int dc = 0; dc < 4; ++dc)
            op[row + dc * 16 + l15] = acc[dc][j] * invl;
    }
}

extern "C" void kernel_launch(void* const* d_in, const int* in_sizes, int n_in,
                              void* d_out, int out_size, void* d_ws, size_t ws_size,
                              hipStream_t stream) {
    const float* q = (const float*)d_in[0];
    const float* k = (const float*)d_in[1];
    const float* v = (const float*)d_in[2];
    float* o = (float*)d_out;
    const int bh = in_sizes[0] / (S_LEN * DK);   // = 32 for B=2,H=16
    dim3 grid(S_LEN / QBLK, bh);
    attn_fwd_kernel<<<grid, dim3(256), 0, stream>>>(q, k, v, o);
}

// Round 3
// 65.549 us; speedup vs baseline: 2.3826x; 1.3622x over previous
//
#include <hip/hip_runtime.h>
#include <hip/hip_bf16.h>
#include <math.h>
#include <stdint.h>

// ScaledDotProductAttention: B=2, H=16, S=2048, D=64, fp32 in/out.
// Flash-attention fwd, bf16 MFMA 32x32x16, swapped QK^T (S^T = K Q^T),
// fully in-register P via cvt_pk_bf16 + permlane32_swap (no P LDS round-trip),
// defer-max (THR=8, log2 domain), double-buffered K/V reg-prefetch staging.
// Block = 256 threads (4 waves); wave owns 32 q-rows; block owns 128.
// Grid = (S/128, B*H).

#define S_LEN 2048
#define DK 64
#define QW 32
#define NW 4
#define QBLK (QW * NW)          // 128
#define KVBLK 64
#define NT (S_LEN / KVBLK)      // 32
#define LOG2E 1.44269504088896340736f
#define THR 8.0f

typedef __attribute__((ext_vector_type(16))) float f32x16;
typedef __attribute__((ext_vector_type(8)))  __bf16 bf16x8;
typedef __attribute__((ext_vector_type(4)))  __bf16 bf16x4;
typedef __attribute__((ext_vector_type(4)))  uint32_t u32x4;

union frag_cast { u32x4 u; bf16x8 h; };

__device__ __forceinline__ uint32_t cvt_pk_bf16(float lo, float hi) {
    uint32_t r;
    asm("v_cvt_pk_bf16_f32 %0, %1, %2" : "=v"(r) : "v"(lo), "v"(hi));
    return r;
}
// new a = word for i∈{0,1}(lo-half idx): {a.low lanes keep a; a.high lanes get b.low}
// new b = {b.low lanes get a.high; b.high lanes keep b}
__device__ __forceinline__ void perm32swap(uint32_t& a, uint32_t& b) {
    asm volatile("v_permlane32_swap_b32 %0, %1" : "+v"(a), "+v"(b));
}

__global__ __launch_bounds__(256, 2)
void attn_fwd_kernel(const float* __restrict__ Qg, const float* __restrict__ Kg,
                     const float* __restrict__ Vg, float* __restrict__ Og)
{
    // K tile: row-major [k][d], swizzle: elem = k*64 + (d ^ ((k&7)<<3))
    __shared__ __align__(16) __bf16 Kl[2][64 * 64];
    // V tile: transposed [d][k], swizzle: elem = d*64 + (k ^ ((d&7)<<3))
    __shared__ __align__(16) __bf16 Vt[2][64 * 64];

    const int tid = threadIdx.x;
    const int lane = tid & 63;
    const int w   = tid >> 6;
    const int l31 = lane & 31;
    const int hi  = lane >> 5;

    const int qt = blockIdx.x;
    const int bh = blockIdx.y;
    const size_t base = (size_t)bh * (S_LEN * DK);
    const int q0g = qt * QBLK + w * QW;   // wave's first q row

    // ---- Q fragments (B-operand): lane holds Q[q0g+l31][16*sp + 8*hi + i] ----
    // scale 1/8 * log2(e) folded -> logits in log2 domain.
    bf16x8 qf[4];
    {
        const float sc = 0.125f * LOG2E;
        const float* qrow = Qg + base + (size_t)(q0g + l31) * DK;
        #pragma unroll
        for (int sp = 0; sp < 4; ++sp) {
            const int d0 = 16 * sp + 8 * hi;
            float4 a = *(const float4*)(qrow + d0);
            float4 b = *(const float4*)(qrow + d0 + 4);
            bf16x8 f;
            f[0] = (__bf16)(a.x * sc); f[1] = (__bf16)(a.y * sc);
            f[2] = (__bf16)(a.z * sc); f[3] = (__bf16)(a.w * sc);
            f[4] = (__bf16)(b.x * sc); f[5] = (__bf16)(b.y * sc);
            f[6] = (__bf16)(b.z * sc); f[7] = (__bf16)(b.w * sc);
            qf[sp] = f;
        }
    }

    // O acc: lane holds O[q = (r&3)+8*(r>>2)+4*hi][d = dt*32 + l31], dt=0,1
    f32x16 acc0 = {}, acc1 = {};
    // softmax state for q-column l31 (replicated across hi halves)
    float m_run = -INFINITY, l_run = 0.f;

    // ---- staging prefetch regs ----
    float4 kpre[4];
    float  vpre[4][4];
    const int vd  = tid & 63;
    const int vkq = tid >> 6;

    auto issueLoads = [&](int t) {
        const int kv0 = t * KVBLK;
        #pragma unroll
        for (int i = 0; i < 4; ++i) {
            const int idx = tid + 256 * i;
            const int r = idx >> 4, c = idx & 15;
            kpre[i] = *(const float4*)(Kg + base + (size_t)(kv0 + r) * DK + c * 4);
        }
        #pragma unroll
        for (int i = 0; i < 4; ++i) {
            const int k0 = vkq * 4 + 16 * i;
            const float* vp = Vg + base + (size_t)(kv0 + k0) * DK + vd;
            vpre[i][0] = vp[0];      vpre[i][1] = vp[DK];
            vpre[i][2] = vp[2 * DK]; vpre[i][3] = vp[3 * DK];
        }
    };
    auto writeTile = [&](int b) {
        #pragma unroll
        for (int i = 0; i < 4; ++i) {
            const int idx = tid + 256 * i;
            const int r = idx >> 4, c = idx & 15;
            bf16x4 pk;
            pk[0] = (__bf16)kpre[i].x; pk[1] = (__bf16)kpre[i].y;
            pk[2] = (__bf16)kpre[i].z; pk[3] = (__bf16)kpre[i].w;
            *(bf16x4*)(&Kl[b][r * 64 + ((c * 4) ^ ((r & 7) << 3))]) = pk;
        }
        #pragma unroll
        for (int i = 0; i < 4; ++i) {
            const int k0 = vkq * 4 + 16 * i;
            bf16x4 pv;
            pv[0] = (__bf16)vpre[i][0]; pv[1] = (__bf16)vpre[i][1];
            pv[2] = (__bf16)vpre[i][2]; pv[3] = (__bf16)vpre[i][3];
            *(bf16x4*)(&Vt[b][vd * 64 + (k0 ^ ((vd & 7) << 3))]) = pv;
        }
    };

    issueLoads(0);
    writeTile(0);
    __syncthreads();

    int cur = 0;
    #pragma unroll 1
    for (int t = 0; t < NT; ++t) {
        if (t + 1 < NT) issueLoads(t + 1);

        // ---- S^T = K Q^T : s{kt}: rows k = kt*32 + (r&3)+8*(r>>2)+4*hi, col q=l31
        f32x16 s0 = {}, s1 = {};
        __builtin_amdgcn_s_setprio(1);
        #pragma unroll
        for (int sp = 0; sp < 4; ++sp) {
            #pragma unroll
            for (int kt = 0; kt < 2; ++kt) {
                const int krow = kt * 32 + l31;
                const int eo = krow * 64 + ((16 * sp + 8 * hi) ^ ((krow & 7) << 3));
                bf16x8 kb = *(const bf16x8*)(&Kl[cur][eo]);
                if (kt == 0) s0 = __builtin_amdgcn_mfma_f32_32x32x16_bf16(kb, qf[sp], s0, 0, 0, 0);
                else         s1 = __builtin_amdgcn_mfma_f32_32x32x16_bf16(kb, qf[sp], s1, 0, 0, 0);
            }
        }
        __builtin_amdgcn_s_setprio(0);

        // ---- lane-local online softmax (q = l31), defer-max ----
        float vmax = -INFINITY;
        #pragma unroll
        for (int j = 0; j < 16; ++j) vmax = fmaxf(vmax, s0[j]);
        #pragma unroll
        for (int j = 0; j < 16; ++j) vmax = fmaxf(vmax, s1[j]);
        vmax = fmaxf(vmax, __shfl_xor(vmax, 32));

        if (!__all(vmax - m_run <= THR)) {
            const float mnew = fmaxf(m_run, vmax);
            const float alpha = __builtin_amdgcn_exp2f(m_run - mnew);
            m_run = mnew;
            l_run *= alpha;
            #pragma unroll
            for (int r = 0; r < 16; ++r) {
                const int ql = (r & 3) + 8 * (r >> 2) + 4 * hi;
                const float ar = __shfl(alpha, ql + (hi << 5));
                acc0[r] *= ar;
                acc1[r] *= ar;
            }
        }

        float rs = 0.f;
        #pragma unroll
        for (int j = 0; j < 16; ++j) { const float p = __builtin_amdgcn_exp2f(s0[j] - m_run); s0[j] = p; rs += p; }
        #pragma unroll
        for (int j = 0; j < 16; ++j) { const float p = __builtin_amdgcn_exp2f(s1[j] - m_run); s1[j] = p; rs += p; }
        rs += __shfl_xor(rs, 32);
        l_run += rs;

        // ---- P -> bf16 A-frags in-register (cvt_pk + permlane32_swap) ----
        // pa[ks] covers k in [16*ks, 16*ks+16): lane holds P[q=l31... as A[row=l31? no:
        // A-frag: lane l holds A[l&31][8*hi + i] -> P[q][16*ks + 8*hi + i] for its q.
        frag_cast pa[4];
        #pragma unroll
        for (int b2 = 0; b2 < 2; ++b2) {
            #pragma unroll
            for (int st = 0; st < 2; ++st) {
                uint32_t wa, wb, wc, wd;
                if (b2 == 0) {
                    wa = cvt_pk_bf16(s0[8 * st + 0], s0[8 * st + 1]);
                    wb = cvt_pk_bf16(s0[8 * st + 2], s0[8 * st + 3]);
                    wc = cvt_pk_bf16(s0[8 * st + 4], s0[8 * st + 5]);
                    wd = cvt_pk_bf16(s0[8 * st + 6], s0[8 * st + 7]);
                } else {
                    wa = cvt_pk_bf16(s1[8 * st + 0], s1[8 * st + 1]);
                    wb = cvt_pk_bf16(s1[8 * st + 2], s1[8 * st + 3]);
                    wc = cvt_pk_bf16(s1[8 * st + 4], s1[8 * st + 5]);
                    wd = cvt_pk_bf16(s1[8 * st + 6], s1[8 * st + 7]);
                }
                perm32swap(wa, wc);   // wa -> word0, wc -> word2
                perm32swap(wb, wd);   // wb -> word1, wd -> word3
                pa[2 * b2 + st].u = (u32x4){wa, wb, wc, wd};
            }
        }

        // ---- O += P V ----
        __builtin_amdgcn_s_setprio(1);
        #pragma unroll
        for (int ks = 0; ks < 4; ++ks) {
            #pragma unroll
            for (int dt = 0; dt < 2; ++dt) {
                const int d = dt * 32 + l31;
                const int eo = d * 64 + ((16 * ks + 8 * hi) ^ ((d & 7) << 3));
                bf16x8 vb = *(const bf16x8*)(&Vt[cur][eo]);
                if (dt == 0) acc0 = __builtin_amdgcn_mfma_f32_32x32x16_bf16(pa[ks].h, vb, acc0, 0, 0, 0);
                else         acc1 = __builtin_amdgcn_mfma_f32_32x32x16_bf16(pa[ks].h, vb, acc1, 0, 0, 0);
            }
        }
        __builtin_amdgcn_s_setprio(0);

        if (t + 1 < NT) writeTile(cur ^ 1);
        __syncthreads();
        cur ^= 1;
    }

    // ---- epilogue: O = acc / l ----
    float* op = Og + base;
    #pragma unroll
    for (int r = 0; r < 16; ++r) {
        const int ql = (r & 3) + 8 * (r >> 2) + 4 * hi;
        const float lr = __shfl(l_run, ql + (hi << 5));
        const float invl = 1.0f / lr;
        const size_t row = (size_t)(q0g + ql) * DK;
        op[row + l31]      = acc0[r] * invl;
        op[row + 32 + l31] = acc1[r] * invl;
    }
}

extern "C" void kernel_launch(void* const* d_in, const int* in_sizes, int n_in,
                              void* d_out, int out_size, void* d_ws, size_t ws_size,
                              hipStream_t stream) {
    const float* q = (const float*)d_in[0];
    const float* k = (const float*)d_in[1];
    const float* v = (const float*)d_in[2];
    float* o = (float*)d_out;
    const int bh = in_sizes[0] / (S_LEN * DK);   // = 32 for B=2,H=16
    dim3 grid(S_LEN / QBLK, bh);
    attn_fwd_kernel<<<grid, dim3(256), 0, stream>>>(q, k, v, o);
}